// Round 2
// baseline (9833.963 us; speedup 1.0000x reference)
//
#include <hip/hip_runtime.h>
#include <hip/hip_bf16.h>
#include <stdint.h>

#define LL 4096
#define EE 300
#define HH 512
#define G4H 2048
#define TT 11
#define TSTART 9
#define TSTOP 10
#define NEGINF -10000.0f

__device__ __forceinline__ float sigf(float x){
    x = fminf(fmaxf(x, -30.f), 30.f);
    return 1.0f / (1.0f + __expf(-x));
}
__device__ __forceinline__ float tanhfast(float x){
    x = fminf(fmaxf(x, -15.f), 15.f);
    float e = __expf(-2.0f * x);
    return (1.0f - e) / (1.0f + e);
}
__device__ __forceinline__ unsigned long long shfl_u64(unsigned long long v, int src){
    unsigned lo = (unsigned)v, hi = (unsigned)(v >> 32);
    lo = __shfl(lo, src, 64); hi = __shfl(hi, src, 64);
    return ((unsigned long long)hi << 32) | (unsigned long long)lo;
}
__device__ __forceinline__ float readl(float v, int i){
    return __uint_as_float((unsigned)__builtin_amdgcn_readlane((int)__float_as_uint(v), i));
}
__device__ __forceinline__ unsigned long long lda(unsigned long long* p){
    return __hip_atomic_load(p, __ATOMIC_RELAXED, __HIP_MEMORY_SCOPE_AGENT);
}

// ---------------- K0: zero the h-communication buffers (fresh tags each call)
__global__ void k0_zero(unsigned long long* __restrict__ comm){
    int i = blockIdx.x * blockDim.x + threadIdx.x;
    if (i < 2 * 2 * HH) comm[i] = 0ull;
}

// ---------------- K1: xg[dir][t][r] = emb[sent[t]] . w_ih[dir][r] + b_ih[r] + b_hh[r]
// 2 rows per thread: halves LDS-read : FMA ratio vs R1.
__global__ __launch_bounds__(256) void k1_xg(
    const int* __restrict__ sent, const float* __restrict__ emb,
    const float* __restrict__ wih_f, const float* __restrict__ bih_f, const float* __restrict__ bhh_f,
    const float* __restrict__ wih_b, const float* __restrict__ bih_b, const float* __restrict__ bhh_b,
    float* __restrict__ xg_f, float* __restrict__ xg_b)
{
    __shared__ float elds[32 * 304];
    int t0  = blockIdx.x * 32;
    int r0  = blockIdx.y * 256;
    int dir = blockIdx.z;
    const float* wih = dir ? wih_b : wih_f;
    const float* bih = dir ? bih_b : bih_f;
    const float* bhh = dir ? bhh_b : bhh_f;
    float* xg = dir ? xg_b : xg_f;

    for (int idx = threadIdx.x; idx < 32 * EE; idx += 256){
        int i = idx / EE, e = idx - i * EE;
        elds[i * 304 + e] = emb[(long)sent[t0 + i] * EE + e];
    }
    __syncthreads();

    int rA = r0 + (threadIdx.x & 127);
    int rB = rA + 128;
    int half = threadIdx.x >> 7;
    float accA[16], accB[16];
    #pragma unroll
    for (int i = 0; i < 16; i++){ accA[i] = 0.f; accB[i] = 0.f; }
    const float* wrowA = wih + (long)rA * EE;
    const float* wrowB = wih + (long)rB * EE;
    for (int e4 = 0; e4 < 75; e4++){
        float4 wa = *reinterpret_cast<const float4*>(wrowA + e4 * 4);
        float4 wb = *reinterpret_cast<const float4*>(wrowB + e4 * 4);
        #pragma unroll
        for (int i = 0; i < 16; i++){
            float4 ev = *reinterpret_cast<const float4*>(&elds[(half * 16 + i) * 304 + e4 * 4]);
            accA[i] += wa.x * ev.x + wa.y * ev.y + wa.z * ev.z + wa.w * ev.w;
            accB[i] += wb.x * ev.x + wb.y * ev.y + wb.z * ev.z + wb.w * ev.w;
        }
    }
    float bA = bih[rA] + bhh[rA];
    float bB = bih[rB] + bhh[rB];
    #pragma unroll
    for (int i = 0; i < 16; i++){
        int t = t0 + half * 16 + i;
        xg[(long)t * G4H + rA] = accA[i] + bA;
        xg[(long)t * G4H + rB] = accB[i] + bB;
    }
}

// ---------------- K2: persistent BiLSTM. 64 blocks: bid>>5 = dir, bid&31 = j-slice.
// wave w = h-chunk w: polls h[w*64+l] into lane regs (no LDS for h, no staging
// barrier). Dot via v_readlane broadcast (zero LDS traffic). One ds_write_b32
// partial + one barrier; wave0 reduces 8 partials, computes gates, publishes.
__global__ __launch_bounds__(512) void k2_lstm(
    const float* __restrict__ whh_f, const float* __restrict__ whh_b,
    const float* __restrict__ xg_f, const float* __restrict__ xg_b,
    float* __restrict__ hs_f, float* __restrict__ hs_b,
    unsigned long long* __restrict__ comm)
{
    int dir = blockIdx.x >> 5;
    int b   = blockIdx.x & 31;
    int j0  = b * 16;
    int tid = threadIdx.x;
    int w   = tid >> 6;           // wave index = h-chunk
    int l   = tid & 63;           // lane = local row (g*16 + jl)
    int jl  = l & 15;
    int row = (l >> 4) * HH + j0 + jl;   // global row in [0,2048)

    const float* whh = dir ? whh_b : whh_f;
    const float* xg  = dir ? xg_b  : xg_f;
    float* hs        = dir ? hs_b  : hs_f;
    unsigned long long* cm = comm + dir * 2 * HH;

    // weights: this lane's row, columns [w*64, w*64+64)
    float wreg[64];
    {
        const float* wp = whh + (long)row * HH + w * 64;
        #pragma unroll
        for (int i = 0; i < 64; i += 4){
            float4 v = *reinterpret_cast<const float4*>(wp + i);
            wreg[i] = v.x; wreg[i+1] = v.y; wreg[i+2] = v.z; wreg[i+3] = v.w;
        }
    }

    __shared__ float plds[2][512];
    float c = 0.f;

    for (int s = 0; s < LL; ++s){
        int t = dir ? (LL - 1 - s) : s;
        // prefetch xg for the tail (wave0 only); overlaps the poll
        float xgv = 0.f;
        if (w == 0) xgv = xg[(long)t * G4H + row];

        float hreg;
        if (s == 0){
            hreg = 0.f;
        } else {
            unsigned long long* pw = cm + (s & 1) * HH + (w * 64 + l);
            // 4-deep pipelined poll: sample period ~ RT/4 instead of RT
            unsigned long long v0 = lda(pw), v1 = lda(pw), v2 = lda(pw), v3 = lda(pw);
            unsigned want = (unsigned)s;
            while ((unsigned)(v0 >> 32) != want){
                v0 = v1; v1 = v2; v2 = v3; v3 = lda(pw);
            }
            hreg = __uint_as_float((unsigned)v0);
        }

        // dot over this wave's 64-wide h chunk, h broadcast via readlane (SGPR)
        float a0 = 0.f, a1 = 0.f, a2 = 0.f, a3 = 0.f;
        #pragma unroll
        for (int i = 0; i < 64; i += 4){
            a0 += wreg[i]   * readl(hreg, i);
            a1 += wreg[i+1] * readl(hreg, i+1);
            a2 += wreg[i+2] * readl(hreg, i+2);
            a3 += wreg[i+3] * readl(hreg, i+3);
        }
        plds[s & 1][tid] = (a0 + a1) + (a2 + a3);
        __syncthreads();

        if (w == 0){
            float sum = 0.f;
            #pragma unroll
            for (int q = 0; q < 8; q++) sum += plds[s & 1][q * 64 + l];
            float pre = sum + xgv;   // full preact for row l's (gate, jl)
            // gather i,f,g,o preacts for this lane's jl
            float vi = __shfl(pre, jl,      64);
            float vf = __shfl(pre, 16 + jl, 64);
            float vg = __shfl(pre, 32 + jl, 64);
            float vo = __shfl(pre, 48 + jl, 64);
            c = sigf(vf) * c + sigf(vi) * tanhfast(vg);
            float h = sigf(vo) * tanhfast(c);
            if (l < 16){
                union { float f; unsigned u; } hv; hv.f = h;
                unsigned long long pk = ((unsigned long long)(s + 1) << 32)
                                      | (unsigned long long)hv.u;
                __hip_atomic_store(cm + ((s + 1) & 1) * HH + (j0 + l), pk,
                                   __ATOMIC_RELAXED, __HIP_MEMORY_SCOPE_AGENT);
                hs[(long)t * HH + (j0 + l)] = h;
            }
        }
        // waves 1-7 run ahead to the next poll; plds is parity double-buffered,
        // and they cannot reach parity reuse (s+2) before our wave0 passes
        // barrier(s+1), which it only does after reading plds[s&1].
    }
}

// ---------------- K3: feats[t][n] = w_tag[n] . [hf[t], hb[t]] + b_tag[n]
__global__ __launch_bounds__(64) void k3_feats(
    const float* __restrict__ hs_f, const float* __restrict__ hs_b,
    const float* __restrict__ wtag, const float* __restrict__ btag,
    float* __restrict__ feats)
{
    int t = blockIdx.x;
    int lane = threadIdx.x;
    float hreg[16];
    #pragma unroll
    for (int q = 0; q < 16; q++){
        int k = q * 64 + lane;
        hreg[q] = (q < 8) ? hs_f[(long)t * HH + k] : hs_b[(long)t * HH + (k - HH)];
    }
    for (int n = 0; n < TT; n++){
        float a = 0.f;
        #pragma unroll
        for (int q = 0; q < 16; q++){
            a += wtag[n * 1024 + q * 64 + lane] * hreg[q];
        }
        #pragma unroll
        for (int off = 32; off; off >>= 1) a += __shfl_down(a, off, 64);
        if (lane == 0) feats[t * 12 + n] = a + btag[n];
    }
}

// ---------------- K4: Viterbi scan + backtrace on a single wave
__global__ __launch_bounds__(64) void k4_viterbi(
    const float* __restrict__ feats, const float* __restrict__ trans,
    float* __restrict__ out)
{
    __shared__ unsigned long long bplds[LL];
    int lane = threadIdx.x;
    float tr[TT];
    #pragma unroll
    for (int p = 0; p < TT; p++) tr[p] = (lane < TT) ? trans[lane * TT + p] : NEGINF;
    float fv = (lane == TSTART) ? 0.f : NEGINF;

    #define LDF(t) ((lane < TT) ? feats[(t) * 12 + lane] : 0.f)
    float f0 = LDF(0), f1 = LDF(1), f2 = LDF(2), f3 = LDF(3);

    for (int t = 0; t < LL; t += 4){
        #define VSTEP(FT, TNEXT, TCUR) { \
            float best = __shfl(fv, 0, 64) + tr[0]; int bp = 0; \
            _Pragma("unroll") \
            for (int p = 1; p < TT; p++){ \
                float sp = __shfl(fv, p, 64) + tr[p]; \
                if (sp > best){ best = sp; bp = p; } \
            } \
            unsigned lo = (lane < 8) ? ((unsigned)bp << (4 * lane)) : 0u; \
            unsigned hi = (lane >= 8 && lane < TT) ? ((unsigned)bp << (4 * (lane - 8))) : 0u; \
            _Pragma("unroll") \
            for (int off = 1; off < 16; off <<= 1){ \
                lo |= __shfl_xor(lo, off, 16); hi |= __shfl_xor(hi, off, 16); \
            } \
            if (lane == 0) bplds[TCUR] = (unsigned long long)lo | ((unsigned long long)hi << 32); \
            fv = best + FT; \
            FT = ((TNEXT) < LL) ? LDF(TNEXT) : 0.f; \
        }
        VSTEP(f0, t + 4, t)
        VSTEP(f1, t + 5, t + 1)
        VSTEP(f2, t + 6, t + 2)
        VSTEP(f3, t + 7, t + 3)
        #undef VSTEP
    }
    __syncthreads();

    float term = (lane < TT) ? (fv + trans[TSTOP * TT + lane]) : -3.0e38f;
    int idx = (lane < TT) ? lane : 63;
    #pragma unroll
    for (int off = 32; off; off >>= 1){
        float os = __shfl_down(term, off, 64);
        int   oi = __shfl_down(idx,  off, 64);
        if (os > term || (os == term && oi < idx)){ term = os; idx = oi; }
    }
    term = __shfl(term, 0, 64);
    idx  = __shfl(idx,  0, 64);
    if (lane == 0){
        out[0] = term;                  // path_score
        out[1 + (LL - 1)] = (float)idx; // path[L-1]
    }

    // backtrace: bp table register-resident (lane holds bplds[i*64+lane]),
    // per-step value broadcast via shfl; tag chain is uniform across lanes.
    unsigned long long bpr[64];
    #pragma unroll
    for (int i = 0; i < 64; i++) bpr[i] = bplds[i * 64 + lane];
    int tag = idx;
    #pragma unroll
    for (int i = 63; i >= 0; --i){
        for (int l2 = 63; l2 >= 0; --l2){
            int u = i * 64 + l2;
            if (u == 0) break;
            unsigned long long wv = shfl_u64(bpr[i], l2);
            tag = (int)((wv >> (4 * tag)) & 15ull);
            if (lane == 0) out[u] = (float)tag;  // out[1 + (u-1)]
        }
    }
}

__global__ void k_dbg(float* out, float v){ out[0] = v; }

extern "C" void kernel_launch(void* const* d_in, const int* in_sizes, int n_in,
                              void* d_out, int out_size, void* d_ws, size_t ws_size,
                              hipStream_t stream)
{
    const int*   sent  = (const int*)  d_in[0];
    const float* emb   = (const float*)d_in[1];
    const float* wih_f = (const float*)d_in[2];
    const float* whh_f = (const float*)d_in[3];
    const float* bih_f = (const float*)d_in[4];
    const float* bhh_f = (const float*)d_in[5];
    const float* wih_b = (const float*)d_in[6];
    const float* whh_b = (const float*)d_in[7];
    const float* bih_b = (const float*)d_in[8];
    const float* bhh_b = (const float*)d_in[9];
    const float* wtag  = (const float*)d_in[10];
    const float* btag  = (const float*)d_in[11];
    const float* trans = (const float*)d_in[12];
    float* out = (float*)d_out;

    char* ws = (char*)d_ws;
    size_t off = 0;
    float* xg_f = (float*)(ws + off); off += (size_t)LL * G4H * 4;
    float* xg_b = (float*)(ws + off); off += (size_t)LL * G4H * 4;
    float* hs_f = (float*)(ws + off); off += (size_t)LL * HH * 4;
    float* hs_b = (float*)(ws + off); off += (size_t)LL * HH * 4;
    float* feats= (float*)(ws + off); off += (size_t)LL * 12 * 4;
    unsigned long long* comm = (unsigned long long*)(ws + off); off += 2 * 2 * HH * 8;

    if (off > ws_size){
        k_dbg<<<1, 1, 0, stream>>>(out, (float)ws_size);
        return;
    }

    k0_zero<<<8, 256, 0, stream>>>(comm);
    k1_xg<<<dim3(128, 8, 2), 256, 0, stream>>>(sent, emb, wih_f, bih_f, bhh_f,
                                               wih_b, bih_b, bhh_b, xg_f, xg_b);
    k2_lstm<<<64, 512, 0, stream>>>(whh_f, whh_b, xg_f, xg_b, hs_f, hs_b, comm);
    k3_feats<<<LL, 64, 0, stream>>>(hs_f, hs_b, wtag, btag, feats);
    k4_viterbi<<<1, 64, 0, stream>>>(feats, trans, out);
}